// Round 8
// baseline (115.208 us; speedup 1.0000x reference)
//
#include <hip/hip_runtime.h>
#include <hip/hip_bf16.h>
#include <stdint.h>

#define AS1 __attribute__((address_space(1)))
#define AS3 __attribute__((address_space(3)))

typedef __attribute__((ext_vector_type(8))) short bf16x8_t;
typedef __attribute__((ext_vector_type(4))) float f32x4_t;

#define DDIM 1024
#define WT_ELEMS ((size_t)DDIM * DDIM)   // 1 Mi bf16 = 2 MiB
#define XB_ELEMS ((size_t)8192 * DDIM)   // 8 Mi bf16 = 16 MiB

// fp32 -> bf16 round-to-nearest-even (truncation bias over K=1024 would eat
// most of the 0.165 absmax budget).
static __device__ inline ushort f32_to_bf16_rne(float f) {
  union { float f; uint32_t u; } v;
  v.f = f;
  v.u += 0x7FFFu + ((v.u >> 16) & 1u);
  return (ushort)(v.u >> 16);
}

// ---------------------------------------------------------------------------
// Fragment-ordered layouts (the whole point of round 8):
//   FA[m16][k32][lane] : 16 B entry = bf16 X[m16*16 + (lane&15)][k32*32 + (lane>>4)*8 + j]
//   FB[n16][k32][lane] : 16 B entry = bf16 W[k32*32 + (lane>>4)*8 + j][n16*16 + (lane&15)]
// A wave's MFMA fragment load becomes ONE fully-coalesced global_load_dwordx4
// (addr = base + lane*16). The GEMM needs no LDS and no barriers at all.
// Entry strides (ushorts): granule16 -> 32*512 = 16384, k32 -> 512.
// ---------------------------------------------------------------------------

// Fused one-time prep (single dispatch):
//   blocks [0, nx):       X (fp32) -> FA   (one block per 16-row strip)
//   blocks [nx, nx+256):  W (fp32) -> FB   (64x64 transpose tiles)
__global__ __launch_bounds__(256) void prep(const float* __restrict__ X,
                                            const float* __restrict__ W,
                                            ushort* __restrict__ FA,
                                            ushort* __restrict__ FB,
                                            int nx) {
  __shared__ ushort xbuf[16][1032];  // 16 rows x (1024 + 8 pad) bf16
  __shared__ float  wtile[64][65];
  const int t = threadIdx.x;

  if ((int)blockIdx.x < nx) {
    // ---- X -> FA: strip of 16 rows x 1024 cols ----
    const int m16 = blockIdx.x;
    const float* src = X + (size_t)m16 * 16 * DDIM;
#pragma unroll
    for (int rep = 0; rep < 16; ++rep) {
      const int fl = ((rep << 8) + t) << 2;         // 0..16380, step 4
      const float4 v = *(const float4*)(src + fl);
      const int r = fl >> 10, c = fl & 1023;
      xbuf[r][c + 0] = f32_to_bf16_rne(v.x);
      xbuf[r][c + 1] = f32_to_bf16_rne(v.y);
      xbuf[r][c + 2] = f32_to_bf16_rne(v.z);
      xbuf[r][c + 3] = f32_to_bf16_rne(v.w);
    }
    __syncthreads();
    ushort* dst = FA + (size_t)m16 * 16384;
#pragma unroll
    for (int rep = 0; rep < 8; ++rep) {
      const int e    = (rep << 8) + t;              // 0..2047
      const int k32  = e >> 6;
      const int lane = e & 63;
      const int fr   = lane & 15, fq = lane >> 4;
      const uint4 u = *(const uint4*)&xbuf[fr][(k32 << 5) + (fq << 3)];
      *(uint4*)(dst + (size_t)e * 8) = u;
    }
    return;
  }

  // ---- W -> FB: 64x64 tile (bk = k-tile, bn = n-tile) ----
  const int bid = (int)blockIdx.x - nx;
  const int bk = bid & 15;
  const int bn = bid >> 4;
#pragma unroll
  for (int s = 0; s < 4; ++s) {
    const int slot = (s << 8) + t;
    const int r    = slot >> 4;
    const int c4   = (slot & 15) << 2;
    const float4 v = *(const float4*)(W + (size_t)(bk * 64 + r) * DDIM + bn * 64 + c4);
    wtile[r][c4 + 0] = v.x; wtile[r][c4 + 1] = v.y;
    wtile[r][c4 + 2] = v.z; wtile[r][c4 + 3] = v.w;
  }
  __syncthreads();
#pragma unroll
  for (int rep = 0; rep < 2; ++rep) {
    const int e    = (rep << 8) + t;                // 0..511
    const int lane = e & 63;
    const int gh   = e >> 6;                        // 0..7
    const int g = gh >> 1, h = gh & 1;
    const int fr = lane & 15, fq = lane >> 4;
    const int lkb = (h << 5) + (fq << 3);           // local k base 0..56
    union { ushort h8[8]; uint4 u; } tmp;
#pragma unroll
    for (int j = 0; j < 8; ++j)
      tmp.h8[j] = f32_to_bf16_rne(wtile[lkb + j][(g << 4) + fr]);
    const size_t n16 = (size_t)(bn << 2) + g;
    const size_t k32 = (size_t)(bk << 1) + h;
    *(uint4*)(FB + (n16 * 32 + k32) * 512 + (size_t)lane * 8) = tmp.u;
  }
}

// ---------------------------------------------------------------------------
// LDS-free GEMM: C[fp32 8192x1024] = X * W  (inputs in fragment order).
// 256 threads = 4 waves in 2x2, wave tile 64x64 (4x4 frags of 16x16x32).
// Grid 64x8 = 512 blocks = 2 blocks/CU, all-resident. No __syncthreads, no
// LDS: each wave streams its fragments via coalesced global_load_dwordx4
// (ping-pong 1-step prefetch); compiler pipelines with fine-grained vmcnt —
// the thing the barrier-coupled m97 structure could never express.
// L2 locality: default dispatch => XCD = blockIdx.x % 8, so the 8 blocks
// sharing each A granule (same m, all n) land on ONE XCD; per-XCD working
// set = 2 MB A-slice + 2 MB B, fits the 4 MB L2.
// ---------------------------------------------------------------------------
__global__ __launch_bounds__(256, 2) void gemm_frag(const ushort* __restrict__ FA,
                                                    const ushort* __restrict__ FB,
                                                    float* __restrict__ C) {
  const int t    = threadIdx.x;
  const int wave = t >> 6;
  const int lane = t & 63;
  const int m0 = blockIdx.x * 128;
  const int n0 = blockIdx.y * 128;
  const int wr = (wave >> 1) << 6;
  const int wc = (wave & 1) << 6;
  const int fr = lane & 15;
  const int fq = lane >> 4;

  const ushort* pa = FA + (size_t)((m0 + wr) >> 4) * 16384 + (size_t)lane * 8;
  const ushort* pb = FB + (size_t)((n0 + wc) >> 4) * 16384 + (size_t)lane * 8;

  bf16x8_t a0[4], b0[4], a1[4], b1[4];
  f32x4_t acc[4][4] = {};

#define LD(ar, br, s)                                                          \
  {                                                                            \
    const ushort* qa = pa + (size_t)(s) * 512;                                 \
    const ushort* qb = pb + (size_t)(s) * 512;                                 \
    _Pragma("unroll") for (int i = 0; i < 4; ++i)                              \
        (ar)[i] = *(const bf16x8_t*)(qa + (size_t)i * 16384);                  \
    _Pragma("unroll") for (int i = 0; i < 4; ++i)                              \
        (br)[i] = *(const bf16x8_t*)(qb + (size_t)i * 16384);                  \
  }
#define MM(ar, br)                                                             \
  {                                                                            \
    _Pragma("unroll") for (int mi = 0; mi < 4; ++mi)                           \
        _Pragma("unroll") for (int ni = 0; ni < 4; ++ni)                       \
            acc[mi][ni] = __builtin_amdgcn_mfma_f32_16x16x32_bf16(             \
                (ar)[mi], (br)[ni], acc[mi][ni], 0, 0, 0);                     \
  }

  LD(a0, b0, 0);
  for (int s2 = 0; s2 < 15; ++s2) {
    LD(a1, b1, 2 * s2 + 1);
    MM(a0, b0);
    LD(a0, b0, 2 * s2 + 2);
    MM(a1, b1);
  }
  LD(a1, b1, 31);
  MM(a0, b0);
  MM(a1, b1);
#undef LD
#undef MM

  // Epilogue (verified R2-R7). C/D layout: col = lane&15, row = (lane>>4)*4+reg.
#pragma unroll
  for (int mi = 0; mi < 4; ++mi) {
#pragma unroll
    for (int r = 0; r < 4; ++r) {
      const int row = m0 + wr + (mi << 4) + (fq << 2) + r;
      float* crow = C + (size_t)row * DDIM + n0 + wc + fr;
#pragma unroll
      for (int ni = 0; ni < 4; ++ni)
        crow[ni << 4] = acc[mi][ni][r];
    }
  }
}

// ---------------------------------------------------------------------------
// Fallback path (ws too small for FA+FB): round-2 kernels, row-major Wt.
// ---------------------------------------------------------------------------
__global__ __launch_bounds__(256) void transpose_w(const float* __restrict__ W,
                                                   ushort* __restrict__ Wt) {
  __shared__ float tile[64][65];
  const int t  = threadIdx.x;
  const int bk = blockIdx.x;
  const int bn = blockIdx.y;
#pragma unroll
  for (int s = 0; s < 4; ++s) {
    const int slot = (s << 8) + t;
    const int r    = slot >> 4;
    const int c4   = (slot & 15) << 2;
    const float4 v = *(const float4*)(W + (size_t)(bk * 64 + r) * DDIM + bn * 64 + c4);
    tile[r][c4 + 0] = v.x; tile[r][c4 + 1] = v.y;
    tile[r][c4 + 2] = v.z; tile[r][c4 + 3] = v.w;
  }
  __syncthreads();
#pragma unroll
  for (int s = 0; s < 2; ++s) {
    const int slot = (s << 8) + t;
    const int n    = slot >> 3;
    const int k8   = (slot & 7) << 3;
    union { ushort h[8]; uint4 u; } tmp;
#pragma unroll
    for (int j = 0; j < 8; ++j) tmp.h[j] = f32_to_bf16_rne(tile[k8 + j][n]);
    *(uint4*)(Wt + (size_t)(bn * 64 + n) * DDIM + bk * 64 + k8) = tmp.u;
  }
}

__global__ __launch_bounds__(256) void gemm_xw(const float* __restrict__ X,
                                               const ushort* __restrict__ Wt,
                                               float* __restrict__ C) {
  __shared__ __align__(16) ushort As[128 * 32];
  __shared__ __align__(16) ushort Bs[128 * 32];
  const int t    = threadIdx.x;
  const int wave = t >> 6;
  const int lane = t & 63;
  const int m0 = blockIdx.x * 128;
  const int n0 = blockIdx.y * 128;
  const int srow  = (wave << 4) + (lane >> 2);
  const int skcol = (lane & 3) << 3;
  const ushort* bptr0 = Wt + (size_t)(n0 + srow) * DDIM + skcol;
  const ushort* bptr1 = Wt + (size_t)(n0 + 64 + srow) * DDIM + skcol;
  const int ar = t >> 2;
  const int ak = (t & 3) << 3;
  const float* aptr0 = X + (size_t)(m0 + ar) * DDIM + ak;
  const float* aptr1 = X + (size_t)(m0 + 64 + ar) * DDIM + ak;
  ushort* asw0 = &As[(ar << 5) + ak];
  ushort* asw1 = &As[((ar + 64) << 5) + ak];
  const int wr = (wave >> 1) << 6;
  const int wc = (wave & 1) << 6;
  const int fr = lane & 15;
  const int fq = lane >> 4;
  f32x4_t acc[4][4] = {};
  AS3 char* ldsB = (AS3 char*)Bs;
  const int woff = wave << 10;
  for (int kt = 0; kt < DDIM; kt += 32) {
    const float4 a00 = *(const float4*)(aptr0);
    const float4 a01 = *(const float4*)(aptr0 + 4);
    const float4 a10 = *(const float4*)(aptr1);
    const float4 a11 = *(const float4*)(aptr1 + 4);
    aptr0 += 32; aptr1 += 32;
    __syncthreads();
    __builtin_amdgcn_global_load_lds((const AS1 void*)bptr0, (AS3 void*)(ldsB + woff),        16, 0, 0);
    __builtin_amdgcn_global_load_lds((const AS1 void*)bptr1, (AS3 void*)(ldsB + 4096 + woff), 16, 0, 0);
    bptr0 += 32; bptr1 += 32;
    union { ushort h[8]; bf16x8_t v; } c0, c1;
    c0.h[0] = f32_to_bf16_rne(a00.x); c0.h[1] = f32_to_bf16_rne(a00.y);
    c0.h[2] = f32_to_bf16_rne(a00.z); c0.h[3] = f32_to_bf16_rne(a00.w);
    c0.h[4] = f32_to_bf16_rne(a01.x); c0.h[5] = f32_to_bf16_rne(a01.y);
    c0.h[6] = f32_to_bf16_rne(a01.z); c0.h[7] = f32_to_bf16_rne(a01.w);
    c1.h[0] = f32_to_bf16_rne(a10.x); c1.h[1] = f32_to_bf16_rne(a10.y);
    c1.h[2] = f32_to_bf16_rne(a10.z); c1.h[3] = f32_to_bf16_rne(a10.w);
    c1.h[4] = f32_to_bf16_rne(a11.x); c1.h[5] = f32_to_bf16_rne(a11.y);
    c1.h[6] = f32_to_bf16_rne(a11.z); c1.h[7] = f32_to_bf16_rne(a11.w);
    *(bf16x8_t*)asw0 = c0.v;
    *(bf16x8_t*)asw1 = c1.v;
    __syncthreads();
    bf16x8_t af[4], bfr[4];
#pragma unroll
    for (int mi = 0; mi < 4; ++mi)
      af[mi] = *(const bf16x8_t*)&As[((wr + (mi << 4) + fr) << 5) + (fq << 3)];
#pragma unroll
    for (int ni = 0; ni < 4; ++ni)
      bfr[ni] = *(const bf16x8_t*)&Bs[((wc + (ni << 4) + fr) << 5) + (fq << 3)];
#pragma unroll
    for (int mi = 0; mi < 4; ++mi)
#pragma unroll
      for (int ni = 0; ni < 4; ++ni)
        acc[mi][ni] = __builtin_amdgcn_mfma_f32_16x16x32_bf16(af[mi], bfr[ni], acc[mi][ni], 0, 0, 0);
  }
#pragma unroll
  for (int mi = 0; mi < 4; ++mi)
#pragma unroll
    for (int r = 0; r < 4; ++r) {
      const int row = m0 + wr + (mi << 4) + (fq << 2) + r;
      float* crow = C + (size_t)row * DDIM + n0 + wc + fr;
#pragma unroll
      for (int ni = 0; ni < 4; ++ni)
        crow[ni << 4] = acc[mi][ni][r];
    }
}

// ---------------------------------------------------------------------------
// softmax over the size-1 sequence axis == 1.0 exactly -> out = x @ kernel[2].
// ---------------------------------------------------------------------------
extern "C" void kernel_launch(void* const* d_in, const int* in_sizes, int n_in,
                              void* d_out, int out_size, void* d_ws, size_t ws_size,
                              hipStream_t stream) {
  const float* x    = (const float*)d_in[0];
  const float* kern = (const float*)d_in[1];
  const float* W = kern + (size_t)2 * DDIM * DDIM;  // kernel[2] — V projection
  const int M = in_sizes[0] / DDIM;                 // 8192

  if (ws_size >= (WT_ELEMS + XB_ELEMS) * sizeof(ushort)) {
    ushort* FA = (ushort*)d_ws;                     // 16 MiB, fragment order
    ushort* FB = (ushort*)d_ws + XB_ELEMS;          // 2 MiB, fragment order
    const int nx = M / 16;                          // 512 strips
    prep<<<nx + 256, 256, 0, stream>>>(x, W, FA, FB, nx);
    gemm_frag<<<dim3(M / 128, DDIM / 128), 256, 0, stream>>>(FA, FB, (float*)d_out);
  } else {
    ushort* Wt = (ushort*)d_ws;
    transpose_w<<<dim3(16, 16), 256, 0, stream>>>(W, Wt);
    gemm_xw<<<dim3(M / 128, DDIM / 128), 256, 0, stream>>>(x, Wt, (float*)d_out);
  }
}

// Round 9
// 114.060 us; speedup vs baseline: 1.0101x; 1.0101x over previous
//
#include <hip/hip_runtime.h>
#include <hip/hip_bf16.h>
#include <stdint.h>

#define AS1 __attribute__((address_space(1)))
#define AS3 __attribute__((address_space(3)))

typedef __attribute__((ext_vector_type(8))) short bf16x8_t;
typedef __attribute__((ext_vector_type(4))) float f32x4_t;

#define DDIM 1024
#define WT_ELEMS ((size_t)DDIM * DDIM)   // 1 Mi bf16 = 2 MiB
#define XB_ELEMS ((size_t)8192 * DDIM)   // 8 Mi bf16 = 16 MiB

// fp32 -> bf16 round-to-nearest-even (truncation bias over K=1024 would eat
// most of the 0.165 absmax budget).
static __device__ inline ushort f32_to_bf16_rne(float f) {
  union { float f; uint32_t u; } v;
  v.f = f;
  v.u += 0x7FFFu + ((v.u >> 16) & 1u);
  return (ushort)(v.u >> 16);
}

// ---------------------------------------------------------------------------
// Fragment-ordered layouts (R8, verified):
//   FA[m16][k32][lane] : 16 B = bf16 X[m16*16 + (lane&15)][k32*32 + (lane>>4)*8 + j]
//   FB[n16][k32][lane] : 16 B = bf16 W[k32*32 + (lane>>4)*8 + j][n16*16 + (lane&15)]
// Entry strides (ushorts): granule16 -> 16384, k32 -> 512.
// ---------------------------------------------------------------------------

// Fused one-time prep (single dispatch):
//   blocks [0, nx):       X (fp32) -> FA   (one block per 16-row strip)
//   blocks [nx, nx+256):  W (fp32) -> FB   (64x64 transpose tiles)
__global__ __launch_bounds__(256) void prep(const float* __restrict__ X,
                                            const float* __restrict__ W,
                                            ushort* __restrict__ FA,
                                            ushort* __restrict__ FB,
                                            int nx) {
  __shared__ ushort xbuf[16][1032];
  __shared__ float  wtile[64][65];
  const int t = threadIdx.x;

  if ((int)blockIdx.x < nx) {
    const int m16 = blockIdx.x;
    const float* src = X + (size_t)m16 * 16 * DDIM;
#pragma unroll
    for (int rep = 0; rep < 16; ++rep) {
      const int fl = ((rep << 8) + t) << 2;
      const float4 v = *(const float4*)(src + fl);
      const int r = fl >> 10, c = fl & 1023;
      xbuf[r][c + 0] = f32_to_bf16_rne(v.x);
      xbuf[r][c + 1] = f32_to_bf16_rne(v.y);
      xbuf[r][c + 2] = f32_to_bf16_rne(v.z);
      xbuf[r][c + 3] = f32_to_bf16_rne(v.w);
    }
    __syncthreads();
    ushort* dst = FA + (size_t)m16 * 16384;
#pragma unroll
    for (int rep = 0; rep < 8; ++rep) {
      const int e    = (rep << 8) + t;
      const int k32  = e >> 6;
      const int lane = e & 63;
      const int fr   = lane & 15, fq = lane >> 4;
      const uint4 u = *(const uint4*)&xbuf[fr][(k32 << 5) + (fq << 3)];
      *(uint4*)(dst + (size_t)e * 8) = u;
    }
    return;
  }

  const int bid = (int)blockIdx.x - nx;
  const int bk = bid & 15;
  const int bn = bid >> 4;
#pragma unroll
  for (int s = 0; s < 4; ++s) {
    const int slot = (s << 8) + t;
    const int r    = slot >> 4;
    const int c4   = (slot & 15) << 2;
    const float4 v = *(const float4*)(W + (size_t)(bk * 64 + r) * DDIM + bn * 64 + c4);
    wtile[r][c4 + 0] = v.x; wtile[r][c4 + 1] = v.y;
    wtile[r][c4 + 2] = v.z; wtile[r][c4 + 3] = v.w;
  }
  __syncthreads();
#pragma unroll
  for (int rep = 0; rep < 2; ++rep) {
    const int e    = (rep << 8) + t;
    const int lane = e & 63;
    const int gh   = e >> 6;
    const int g = gh >> 1, h = gh & 1;
    const int fr = lane & 15, fq = lane >> 4;
    const int lkb = (h << 5) + (fq << 3);
    union { ushort h8[8]; uint4 u; } tmp;
#pragma unroll
    for (int j = 0; j < 8; ++j)
      tmp.h8[j] = f32_to_bf16_rne(wtile[lkb + j][(g << 4) + fr]);
    const size_t n16 = (size_t)(bn << 2) + g;
    const size_t k32 = (size_t)(bk << 1) + h;
    *(uint4*)(FB + (n16 * 32 + k32) * 512 + (size_t)lane * 8) = tmp.u;
  }
}

// ---------------------------------------------------------------------------
// K-split LDS-free GEMM: C[fp32 8192x1024] = X * W (fragment-ordered inputs).
// R8 diagnosis: 2048 64x64 wave-tiles = 2 waves/SIMD -> depth-1 prefetch
// (~156 cyc MFMA/SIMD) < L2 latency (~200-250 cyc) -> every step exposed.
// Fix: 2 waves per 64x64 tile, each doing HALF of K (16 of 32 k-steps) ->
// 4096 waves = 4 waves/SIMD; ~310 cyc of co-resident MFMA issue per SIMD
// per step covers L2 latency via TLP (m114). Bytes/MFMA ratio (0.5 KB) is
// unchanged - unlike shrinking tiles (the R3 mistake).
// 512 threads = 8 waves; wave w: quadrant q=w&3, k-half kh=w>>2.
// Register budget for 4 waves/SIMD (<=128 VGPR): acc 64 + frags 32 + addr
// ~= 105; no ping-pong (TLP replaces intra-wave prefetch).
// Epilogue: kh=1 waves dump acc to LDS (64 KB), one barrier, kh=0 waves
// add + store. 2 blocks/CU * 64 KB = 128 KB <= 160 KB.
// ---------------------------------------------------------------------------
__global__ __launch_bounds__(512, 4) void gemm_ks(const ushort* __restrict__ FA,
                                                  const ushort* __restrict__ FB,
                                                  float* __restrict__ C) {
  __shared__ __align__(16) float red[4 * 16 * 64 * 4];  // 64 KB

  const int t    = threadIdx.x;
  const int wave = t >> 6;
  const int lane = t & 63;
  const int q  = wave & 3;   // quadrant of the 128x128 block tile
  const int kh = wave >> 2;  // k-half: 0 -> k32 0..15, 1 -> k32 16..31
  const int m0 = blockIdx.x * 128;
  const int n0 = blockIdx.y * 128;
  const int wr = (q >> 1) << 6;
  const int wc = (q & 1) << 6;
  const int fr = lane & 15;
  const int fq = lane >> 4;

  const ushort* pa = FA + (size_t)((m0 + wr) >> 4) * 16384 + (size_t)(kh << 4) * 512 + (size_t)lane * 8;
  const ushort* pb = FB + (size_t)((n0 + wc) >> 4) * 16384 + (size_t)(kh << 4) * 512 + (size_t)lane * 8;

  f32x4_t acc[4][4] = {};

  for (int s = 0; s < 16; ++s) {
    bf16x8_t af[4], bf[4];
#pragma unroll
    for (int i = 0; i < 4; ++i) af[i] = *(const bf16x8_t*)(pa + (size_t)i * 16384);
#pragma unroll
    for (int i = 0; i < 4; ++i) bf[i] = *(const bf16x8_t*)(pb + (size_t)i * 16384);
    pa += 512; pb += 512;
#pragma unroll
    for (int mi = 0; mi < 4; ++mi)
#pragma unroll
      for (int ni = 0; ni < 4; ++ni)
        acc[mi][ni] = __builtin_amdgcn_mfma_f32_16x16x32_bf16(af[mi], bf[ni], acc[mi][ni], 0, 0, 0);
  }

  // K-half reduction through LDS (one barrier total).
  if (kh) {
#pragma unroll
    for (int mi = 0; mi < 4; ++mi)
#pragma unroll
      for (int ni = 0; ni < 4; ++ni)
        *(f32x4_t*)&red[(((q << 4) + (mi << 2) + ni) * 64 + lane) << 2] = acc[mi][ni];
  }
  __syncthreads();
  if (kh) return;

  // Epilogue (kh=0 waves). C/D layout: col = lane&15, row = (lane>>4)*4+reg.
#pragma unroll
  for (int mi = 0; mi < 4; ++mi) {
#pragma unroll
    for (int ni = 0; ni < 4; ++ni) {
      const f32x4_t other = *(const f32x4_t*)&red[(((q << 4) + (mi << 2) + ni) * 64 + lane) << 2];
      acc[mi][ni] += other;
    }
#pragma unroll
    for (int r = 0; r < 4; ++r) {
      const int row = m0 + wr + (mi << 4) + (fq << 2) + r;
      float* crow = C + (size_t)row * DDIM + n0 + wc + fr;
#pragma unroll
      for (int ni = 0; ni < 4; ++ni)
        crow[ni << 4] = acc[mi][ni][r];
    }
  }
}

// ---------------------------------------------------------------------------
// Fallback path (ws too small for FA+FB): round-2 kernels, row-major Wt.
// ---------------------------------------------------------------------------
__global__ __launch_bounds__(256) void transpose_w(const float* __restrict__ W,
                                                   ushort* __restrict__ Wt) {
  __shared__ float tile[64][65];
  const int t  = threadIdx.x;
  const int bk = blockIdx.x;
  const int bn = blockIdx.y;
#pragma unroll
  for (int s = 0; s < 4; ++s) {
    const int slot = (s << 8) + t;
    const int r    = slot >> 4;
    const int c4   = (slot & 15) << 2;
    const float4 v = *(const float4*)(W + (size_t)(bk * 64 + r) * DDIM + bn * 64 + c4);
    tile[r][c4 + 0] = v.x; tile[r][c4 + 1] = v.y;
    tile[r][c4 + 2] = v.z; tile[r][c4 + 3] = v.w;
  }
  __syncthreads();
#pragma unroll
  for (int s = 0; s < 2; ++s) {
    const int slot = (s << 8) + t;
    const int n    = slot >> 3;
    const int k8   = (slot & 7) << 3;
    union { ushort h[8]; uint4 u; } tmp;
#pragma unroll
    for (int j = 0; j < 8; ++j) tmp.h[j] = f32_to_bf16_rne(tile[k8 + j][n]);
    *(uint4*)(Wt + (size_t)(bn * 64 + n) * DDIM + bk * 64 + k8) = tmp.u;
  }
}

__global__ __launch_bounds__(256) void gemm_xw(const float* __restrict__ X,
                                               const ushort* __restrict__ Wt,
                                               float* __restrict__ C) {
  __shared__ __align__(16) ushort As[128 * 32];
  __shared__ __align__(16) ushort Bs[128 * 32];
  const int t    = threadIdx.x;
  const int wave = t >> 6;
  const int lane = t & 63;
  const int m0 = blockIdx.x * 128;
  const int n0 = blockIdx.y * 128;
  const int srow  = (wave << 4) + (lane >> 2);
  const int skcol = (lane & 3) << 3;
  const ushort* bptr0 = Wt + (size_t)(n0 + srow) * DDIM + skcol;
  const ushort* bptr1 = Wt + (size_t)(n0 + 64 + srow) * DDIM + skcol;
  const int ar = t >> 2;
  const int ak = (t & 3) << 3;
  const float* aptr0 = X + (size_t)(m0 + ar) * DDIM + ak;
  const float* aptr1 = X + (size_t)(m0 + 64 + ar) * DDIM + ak;
  ushort* asw0 = &As[(ar << 5) + ak];
  ushort* asw1 = &As[((ar + 64) << 5) + ak];
  const int wr = (wave >> 1) << 6;
  const int wc = (wave & 1) << 6;
  const int fr = lane & 15;
  const int fq = lane >> 4;
  f32x4_t acc[4][4] = {};
  AS3 char* ldsB = (AS3 char*)Bs;
  const int woff = wave << 10;
  for (int kt = 0; kt < DDIM; kt += 32) {
    const float4 a00 = *(const float4*)(aptr0);
    const float4 a01 = *(const float4*)(aptr0 + 4);
    const float4 a10 = *(const float4*)(aptr1);
    const float4 a11 = *(const float4*)(aptr1 + 4);
    aptr0 += 32; aptr1 += 32;
    __syncthreads();
    __builtin_amdgcn_global_load_lds((const AS1 void*)bptr0, (AS3 void*)(ldsB + woff),        16, 0, 0);
    __builtin_amdgcn_global_load_lds((const AS1 void*)bptr1, (AS3 void*)(ldsB + 4096 + woff), 16, 0, 0);
    bptr0 += 32; bptr1 += 32;
    union { ushort h[8]; bf16x8_t v; } c0, c1;
    c0.h[0] = f32_to_bf16_rne(a00.x); c0.h[1] = f32_to_bf16_rne(a00.y);
    c0.h[2] = f32_to_bf16_rne(a00.z); c0.h[3] = f32_to_bf16_rne(a00.w);
    c0.h[4] = f32_to_bf16_rne(a01.x); c0.h[5] = f32_to_bf16_rne(a01.y);
    c0.h[6] = f32_to_bf16_rne(a01.z); c0.h[7] = f32_to_bf16_rne(a01.w);
    c1.h[0] = f32_to_bf16_rne(a10.x); c1.h[1] = f32_to_bf16_rne(a10.y);
    c1.h[2] = f32_to_bf16_rne(a10.z); c1.h[3] = f32_to_bf16_rne(a10.w);
    c1.h[4] = f32_to_bf16_rne(a11.x); c1.h[5] = f32_to_bf16_rne(a11.y);
    c1.h[6] = f32_to_bf16_rne(a11.z); c1.h[7] = f32_to_bf16_rne(a11.w);
    *(bf16x8_t*)asw0 = c0.v;
    *(bf16x8_t*)asw1 = c1.v;
    __syncthreads();
    bf16x8_t af[4], bfr[4];
#pragma unroll
    for (int mi = 0; mi < 4; ++mi)
      af[mi] = *(const bf16x8_t*)&As[((wr + (mi << 4) + fr) << 5) + (fq << 3)];
#pragma unroll
    for (int ni = 0; ni < 4; ++ni)
      bfr[ni] = *(const bf16x8_t*)&Bs[((wc + (ni << 4) + fr) << 5) + (fq << 3)];
#pragma unroll
    for (int mi = 0; mi < 4; ++mi)
#pragma unroll
      for (int ni = 0; ni < 4; ++ni)
        acc[mi][ni] = __builtin_amdgcn_mfma_f32_16x16x32_bf16(af[mi], bfr[ni], acc[mi][ni], 0, 0, 0);
  }
#pragma unroll
  for (int mi = 0; mi < 4; ++mi)
#pragma unroll
    for (int r = 0; r < 4; ++r) {
      const int row = m0 + wr + (mi << 4) + (fq << 2) + r;
      float* crow = C + (size_t)row * DDIM + n0 + wc + fr;
#pragma unroll
      for (int ni = 0; ni < 4; ++ni)
        crow[ni << 4] = acc[mi][ni][r];
    }
}

// ---------------------------------------------------------------------------
// softmax over the size-1 sequence axis == 1.0 exactly -> out = x @ kernel[2].
// ---------------------------------------------------------------------------
extern "C" void kernel_launch(void* const* d_in, const int* in_sizes, int n_in,
                              void* d_out, int out_size, void* d_ws, size_t ws_size,
                              hipStream_t stream) {
  const float* x    = (const float*)d_in[0];
  const float* kern = (const float*)d_in[1];
  const float* W = kern + (size_t)2 * DDIM * DDIM;  // kernel[2] — V projection
  const int M = in_sizes[0] / DDIM;                 // 8192

  if (ws_size >= (WT_ELEMS + XB_ELEMS) * sizeof(ushort)) {
    ushort* FA = (ushort*)d_ws;                     // 16 MiB, fragment order
    ushort* FB = (ushort*)d_ws + XB_ELEMS;          // 2 MiB, fragment order
    const int nx = M / 16;                          // 512 strips
    prep<<<nx + 256, 256, 0, stream>>>(x, W, FA, FB, nx);
    gemm_ks<<<dim3(M / 128, DDIM / 128), 512, 0, stream>>>(FA, FB, (float*)d_out);
  } else {
    ushort* Wt = (ushort*)d_ws;
    transpose_w<<<dim3(16, 16), 256, 0, stream>>>(W, Wt);
    gemm_xw<<<dim3(M / 128, DDIM / 128), 256, 0, stream>>>(x, Wt, (float*)d_out);
  }
}